// Round 7
// baseline (1526.331 us; speedup 1.0000x reference)
//
#include <hip/hip_runtime.h>
#include <cstdint>
#include <cstddef>

#define NCLS 5
#define NB   256          // persistent blocks (1 per CU guaranteed co-resident)

typedef unsigned short ushort_t;
typedef __attribute__((ext_vector_type(8))) short short8v;   // 8 bf16 (4 VGPRs)
typedef __attribute__((ext_vector_type(4))) float f32x4;     // MFMA accumulator

__device__ __forceinline__ float sigf(float x) { return 1.0f / (1.0f + __expf(-x)); }

__device__ __forceinline__ unsigned short bf16_rne(float x) {
    unsigned u = __float_as_uint(x);
    u += 0x7FFFu + ((u >> 16) & 1u);
    return (unsigned short)(u >> 16);
}
__device__ __forceinline__ float bf16_f32(unsigned short h) {
    return __uint_as_float(((unsigned)h) << 16);
}

__device__ __forceinline__ void cvt_hilo(float4 f0, float4 f1, short8v& hi, short8v& lo) {
    float v[8] = { f0.x, f0.y, f0.z, f0.w, f1.x, f1.y, f1.z, f1.w };
#pragma unroll
    for (int e = 0; e < 8; ++e) {
        unsigned short h = bf16_rne(v[e]);
        unsigned short l = bf16_rne(v[e] - bf16_f32(h));
        hi[e] = (short)h; lo[e] = (short)l;
    }
}

// direct-to-LDS 16B copy: per-lane global src, wave-uniform LDS dst (+lane*16)
__device__ __forceinline__ void glds16(const ushort_t* g, ushort_t* l) {
    __builtin_amdgcn_global_load_lds((const __attribute__((address_space(1))) void*)g,
                                     (__attribute__((address_space(3))) void*)l,
                                     16, 0, 0);
}

// ---------------------------------------------------------------------------
// Weight prep (same tables as round 6 — fragment-ordered, f1/f2 packed).
// Level WtPL[cb 8][cc 16][slot 4][lane 64][e 8]:
//   band=cc>>3 (hi/lo), c8=cc&7, csel=c8>>2, kc=(c8&3)*32+kq
//   slot 0..2 = Ui/Uo/Uu at K=csel*128+kc; slot 3 = csel? Uf2[kc] : Uf1[kc]
// Leaf WtPF[cb 8][cc 8][slot 3][lane][e]: band=cc>>2, kc=(cc&3)*32+kq
// ---------------------------------------------------------------------------
__global__ __launch_bounds__(256)
void prep_w(const float* __restrict__ Wi, const float* __restrict__ Wo,
            const float* __restrict__ Wu,
            const float* __restrict__ Ui, const float* __restrict__ Uo,
            const float* __restrict__ Uu, const float* __restrict__ Uf1,
            const float* __restrict__ Uf2,
            ushort_t* __restrict__ WtPL, ushort_t* __restrict__ WtPF)
{
    int b = blockIdx.x;
    if (b < 1024) {
        int idx = b * 256 + threadIdx.x;              // 262144
        int e = idx & 7, lane = (idx >> 3) & 63;
        int slot = (idx >> 9) & 3, cc = (idx >> 11) & 15, cb = idx >> 15;
        int j  = cb * 16 + (lane & 15);
        int kq = (lane >> 4) * 8 + e;
        int band = cc >> 3, c8 = cc & 7, csel = c8 >> 2;
        int kc = (c8 & 3) * 32 + kq;                  // [0,128)
        float x;
        if      (slot == 0) x = Ui[(csel * 128 + kc) * 128 + j];
        else if (slot == 1) x = Uo[(csel * 128 + kc) * 128 + j];
        else if (slot == 2) x = Uu[(csel * 128 + kc) * 128 + j];
        else                x = csel ? Uf2[kc * 128 + j] : Uf1[kc * 128 + j];
        unsigned short h = bf16_rne(x);
        if (band) h = bf16_rne(x - bf16_f32(h));
        WtPL[idx] = h;
    } else {
        int idx = (b - 1024) * 256 + threadIdx.x;     // 98304
        if (idx >= 98304) return;
        int e = idx & 7, lane = (idx >> 3) & 63;
        int rest = idx >> 9;
        int slot = rest % 3, cc = (rest / 3) & 7, cb = rest / 24;
        int j  = cb * 16 + (lane & 15);
        int kq = (lane >> 4) * 8 + e;
        int band = cc >> 2;
        int kc = (cc & 3) * 32 + kq;                  // [0,128)
        const float* W = (slot == 0) ? Wi : (slot == 1) ? Wo : Wu;
        float x = W[kc * 128 + j];
        unsigned short h = bf16_rne(x);
        if (band) h = bf16_rne(x - bf16_f32(h));
        WtPF[idx] = h;
    }
}

// ---------------------------------------------------------------------------
// Manual device-scope grid barrier (all NB blocks co-resident by construction)
// ---------------------------------------------------------------------------
__device__ __forceinline__ void grid_barrier(unsigned* cnt, unsigned target) {
    __syncthreads();
    __threadfence();                                   // release (wb L2)
    if (threadIdx.x == 0) {
        atomicAdd(cnt, 1u);                            // device scope by default
        while (atomicAdd(cnt, 0u) < target)
            __builtin_amdgcn_s_sleep(8);
    }
    __syncthreads();
    __threadfence();                                   // acquire (inv stale)
}

// ---------------------------------------------------------------------------
// Persistent tree kernel. 256 blocks x 512 thr; block b: cb=b>>5 (gate-col
// slice; B slab lives in LDS for the whole kernel), q=b&31 (row class; the 8
// blocks sharing q sit on XCD q%8 -> A reads hit shared L2).
// Node rows (1 KB): [8 planes h hi16|lo16 = 512B][c f32[128] = 512B].
// Leaf = nodes 0..65535; level ℓ appended after. Write-once per run.
// ---------------------------------------------------------------------------
__global__ __launch_bounds__(512)
void tree_pers(const int* __restrict__ words, const float* __restrict__ emb,
               const ushort_t* __restrict__ WtPL, const ushort_t* __restrict__ WtPF,
               const float* __restrict__ bi,  const float* __restrict__ bo,
               const float* __restrict__ bu,
               const float* __restrict__ bUi, const float* __restrict__ bUo,
               const float* __restrict__ bUu, const float* __restrict__ bf1,
               const float* __restrict__ bf2,
               ushort_t* __restrict__ H2C, unsigned* __restrict__ cnt)
{
    __shared__ ushort_t Bsl[32768];                   // 64 KB
    const int b   = blockIdx.x;
    const int cb  = b >> 5, q = b & 31;
    const int tid = threadIdx.x, lane = tid & 63, w = tid >> 6;
    const int l15 = lane & 15, l4 = lane >> 4;
    const int jcol = cb * 16 + l15;

    // ---- stage leaf slab (24 KB) ----
    {
        const ushort_t* slab = WtPF + (size_t)cb * 12288;
#pragma unroll
        for (int s = 0; s < 3; ++s)
            glds16(slab + (w * 3 + s) * 512 + lane * 8, Bsl + (w * 3 + s) * 512);
        asm volatile("s_waitcnt vmcnt(0)" ::: "memory");
        __syncthreads();
    }

    // ---- leaf: 2048 tiles of 32 rows; gather emb + hi/lo convert in-reg ----
    {
        const float bi_ = bi[jcol], bo_ = bo[jcol], bu_ = bu[jcol];
        for (int T = q + 32 * w; T < 2048; T += NB) {
            const int r0 = T * 32 + l15, r1 = r0 + 16;
            const float* e0 = emb + (size_t)words[r0] * 128;
            const float* e1 = emb + (size_t)words[r1] * 128;

            f32x4 acc[2][3];
#pragma unroll
            for (int fr = 0; fr < 2; ++fr)
#pragma unroll
                for (int g = 0; g < 3; ++g) acc[fr][g] = (f32x4){0.f, 0.f, 0.f, 0.f};

#pragma unroll
            for (int cc = 0; cc < 4; ++cc) {
                const int k = cc * 32 + l4 * 8;
                short8v Ah0, Al0, Ah1, Al1;
                cvt_hilo(*(const float4*)(e0 + k), *(const float4*)(e0 + k + 4), Ah0, Al0);
                cvt_hilo(*(const float4*)(e1 + k), *(const float4*)(e1 + k + 4), Ah1, Al1);
#pragma unroll
                for (int s = 0; s < 3; ++s) {
                    short8v Bh = *(const short8v*)(Bsl + (cc * 3 + s) * 512 + lane * 8);
                    short8v Bw = *(const short8v*)(Bsl + ((cc + 4) * 3 + s) * 512 + lane * 8);
                    acc[0][s] = __builtin_amdgcn_mfma_f32_16x16x32_bf16(Ah0, Bh, acc[0][s], 0, 0, 0);
                    acc[1][s] = __builtin_amdgcn_mfma_f32_16x16x32_bf16(Ah1, Bh, acc[1][s], 0, 0, 0);
                    acc[0][s] = __builtin_amdgcn_mfma_f32_16x16x32_bf16(Al0, Bh, acc[0][s], 0, 0, 0);
                    acc[1][s] = __builtin_amdgcn_mfma_f32_16x16x32_bf16(Al1, Bh, acc[1][s], 0, 0, 0);
                    acc[0][s] = __builtin_amdgcn_mfma_f32_16x16x32_bf16(Ah0, Bw, acc[0][s], 0, 0, 0);
                    acc[1][s] = __builtin_amdgcn_mfma_f32_16x16x32_bf16(Ah1, Bw, acc[1][s], 0, 0, 0);
                }
            }
#pragma unroll
            for (int fr = 0; fr < 2; ++fr)
#pragma unroll
                for (int v = 0; v < 4; ++v) {
                    const int row = T * 32 + fr * 16 + l4 * 4 + v;
                    float iv = sigf(acc[fr][0][v] + bi_);
                    float ov = sigf(acc[fr][1][v] + bo_);
                    float uv = fmaxf(acc[fr][2][v] + bu_, 0.f);
                    float c_ = iv * uv;
                    float h_ = ov * fmaxf(c_, 0.f);
                    const size_t base = (size_t)row * 512;
                    ((float*)(H2C + base + 256))[jcol] = c_;
                    unsigned short hhi = bf16_rne(h_);
                    unsigned short hlo = bf16_rne(h_ - bf16_f32(hhi));
                    H2C[base + cb * 32 + l15]      = hhi;
                    H2C[base + cb * 32 + 16 + l15] = hlo;
                }
        }
    }

    unsigned ph = 1;
    grid_barrier(cnt, ph * NB);

    // ---- stage level slab (64 KB) ----
    {
        const ushort_t* slab = WtPL + (size_t)cb * 32768;
#pragma unroll
        for (int s = 0; s < 8; ++s)
            glds16(slab + (w * 8 + s) * 512 + lane * 8, Bsl + (w * 8 + s) * 512);
        asm volatile("s_waitcnt vmcnt(0)" ::: "memory");
        __syncthreads();
    }

    // ---- 16 levels ----
    const float b0_ = bUi[jcol], b1_ = bUo[jcol], b2_ = bUu[jcol];
    const float b3_ = bf1[jcol], b4_ = bf2[jcol];
    int off_prev = 0, off = 65536, m = 32768;

    for (int lev = 0; lev < 16; ++lev) {
        const int ntile = (m + 31) >> 5;
        for (int T = q + 32 * w; T < ntile; T += NB) {
            int p0 = T * 32 + l15;      if (p0 > m - 1) p0 = m - 1;
            int p1 = T * 32 + 16 + l15; if (p1 > m - 1) p1 = m - 1;
            const ushort_t* r0 = H2C + (size_t)(off_prev + 2 * p0) * 512;
            const ushort_t* r1 = H2C + (size_t)(off_prev + 2 * p1) * 512;

            f32x4 acc[2][5];
#pragma unroll
            for (int fr = 0; fr < 2; ++fr)
#pragma unroll
                for (int g = 0; g < 5; ++g) acc[fr][g] = (f32x4){0.f, 0.f, 0.f, 0.f};

#pragma unroll
            for (int cc = 0; cc < 8; ++cc) {
                const int csel = cc >> 2;
                const int aoff = csel * 512 + ((cc & 3) * 2 + (l4 >> 1)) * 32 + (l4 & 1) * 8;
                short8v Ah0 = *(const short8v*)(r0 + aoff);
                short8v Ah1 = *(const short8v*)(r1 + aoff);
                short8v Al0 = *(const short8v*)(r0 + aoff + 16);
                short8v Al1 = *(const short8v*)(r1 + aoff + 16);
#pragma unroll
                for (int s = 0; s < 4; ++s) {
                    const int col = (s < 3) ? s : 3 + csel;
                    short8v Bh = *(const short8v*)(Bsl + (cc * 4 + s) * 512 + lane * 8);
                    short8v Bw = *(const short8v*)(Bsl + ((cc + 8) * 4 + s) * 512 + lane * 8);
                    acc[0][col] = __builtin_amdgcn_mfma_f32_16x16x32_bf16(Ah0, Bh, acc[0][col], 0, 0, 0);
                    acc[1][col] = __builtin_amdgcn_mfma_f32_16x16x32_bf16(Ah1, Bh, acc[1][col], 0, 0, 0);
                    acc[0][col] = __builtin_amdgcn_mfma_f32_16x16x32_bf16(Al0, Bh, acc[0][col], 0, 0, 0);
                    acc[1][col] = __builtin_amdgcn_mfma_f32_16x16x32_bf16(Al1, Bh, acc[1][col], 0, 0, 0);
                    acc[0][col] = __builtin_amdgcn_mfma_f32_16x16x32_bf16(Ah0, Bw, acc[0][col], 0, 0, 0);
                    acc[1][col] = __builtin_amdgcn_mfma_f32_16x16x32_bf16(Ah1, Bw, acc[1][col], 0, 0, 0);
                }
            }
#pragma unroll
            for (int fr = 0; fr < 2; ++fr)
#pragma unroll
                for (int v = 0; v < 4; ++v) {
                    const int row = T * 32 + fr * 16 + l4 * 4 + v;
                    if (row < m) {
                        float iv  = sigf(acc[fr][0][v] + b0_);
                        float ov  = sigf(acc[fr][1][v] + b1_);
                        float uv  = fmaxf(acc[fr][2][v] + b2_, 0.f);
                        float f1v = sigf(acc[fr][3][v] + b3_);
                        float f2v = sigf(acc[fr][4][v] + b4_);
                        float lC  = ((const float*)(H2C + (size_t)(off_prev + 2 * row)     * 512 + 256))[jcol];
                        float rC  = ((const float*)(H2C + (size_t)(off_prev + 2 * row + 1) * 512 + 256))[jcol];
                        float c_  = fmaf(iv, uv, fmaf(f1v, lC, f2v * rC));
                        float h_  = ov * fmaxf(c_, 0.f);
                        const size_t base = (size_t)(off + row) * 512;
                        ((float*)(H2C + base + 256))[jcol] = c_;
                        unsigned short hhi = bf16_rne(h_);
                        unsigned short hlo = bf16_rne(h_ - bf16_f32(hhi));
                        H2C[base + cb * 32 + l15]      = hhi;
                        H2C[base + cb * 32 + 16 + l15] = hlo;
                    }
                }
        }
        if (lev < 15) {
            ++ph;
            grid_barrier(cnt, ph * NB);
        }
        off_prev = off; off += m; m >>= 1;
    }
}

// ---------------------------------------------------------------------------
// Projection: out[r] = (hi+lo)[r] @ P + bP   (one wave per row, 1KB rows)
// ---------------------------------------------------------------------------
__global__ __launch_bounds__(256)
void proj2(const ushort_t* __restrict__ H2C, const float* __restrict__ P,
           const float* __restrict__ bP, float* __restrict__ out, int total)
{
    int wid  = blockIdx.x * 4 + (threadIdx.x >> 6);
    int lane = threadIdx.x & 63;
    if (wid >= total) return;
    const ushort_t* hr = H2C + (size_t)wid * 512 + (lane >> 3) * 32 + ((2 * lane) & 15);
    float h0 = bf16_f32(hr[0]) + bf16_f32(hr[16]);
    float h1 = bf16_f32(hr[1]) + bf16_f32(hr[17]);
    const int k0 = 2 * lane, k1 = 2 * lane + 1;
    float a[NCLS];
#pragma unroll
    for (int c2 = 0; c2 < NCLS; ++c2)
        a[c2] = fmaf(h0, P[k0 * NCLS + c2], h1 * P[k1 * NCLS + c2]);
    for (int off = 32; off; off >>= 1)
#pragma unroll
        for (int c2 = 0; c2 < NCLS; ++c2) a[c2] += __shfl_down(a[c2], off, 64);
    if (lane == 0)
#pragma unroll
        for (int c2 = 0; c2 < NCLS; ++c2) out[(size_t)wid * NCLS + c2] = a[c2] + bP[c2];
}

// ---------------------------------------------------------------------------
// Host launcher.
// ws: WtPL@0 (512K) | WtPF@524288 (192K) | cnt@720896 (64B) |
//     H2C@1048576: 131072 node-rows x 1KB = 134,217,728  (ends ~135.3 MB)
// ---------------------------------------------------------------------------
extern "C" void kernel_launch(void* const* d_in, const int* in_sizes, int n_in,
                              void* d_out, int out_size, void* d_ws, size_t ws_size,
                              hipStream_t stream)
{
    const int*   words = (const int*)  d_in[0];
    const float* emb   = (const float*)d_in[1];
    const float* Wi  = (const float*)d_in[2];  const float* bi  = (const float*)d_in[3];
    const float* Wo  = (const float*)d_in[4];  const float* bo  = (const float*)d_in[5];
    const float* Wu  = (const float*)d_in[6];  const float* bu  = (const float*)d_in[7];
    const float* Ui  = (const float*)d_in[8];  const float* bUi = (const float*)d_in[9];
    const float* Uo  = (const float*)d_in[10]; const float* bUo = (const float*)d_in[11];
    const float* Uu  = (const float*)d_in[12]; const float* bUu = (const float*)d_in[13];
    const float* Uf1 = (const float*)d_in[14]; const float* bf1 = (const float*)d_in[15];
    const float* Uf2 = (const float*)d_in[16]; const float* bf2 = (const float*)d_in[17];
    const float* Pm  = (const float*)d_in[18]; const float* bP  = (const float*)d_in[19];
    float* out = (float*)d_out;

    ushort_t* WtPL = (ushort_t*)d_ws;
    ushort_t* WtPF = (ushort_t*)((char*)d_ws + 524288);
    unsigned* cnt  = (unsigned*)((char*)d_ws + 720896);
    ushort_t* H2C  = (ushort_t*)((char*)d_ws + 1048576);

    hipMemsetAsync(cnt, 0, 64, stream);
    prep_w<<<1408, 256, 0, stream>>>(Wi, Wo, Wu, Ui, Uo, Uu, Uf1, Uf2, WtPL, WtPF);

    tree_pers<<<NB, 512, 0, stream>>>(words, emb, WtPL, WtPF,
                                      bi, bo, bu, bUi, bUo, bUu, bf1, bf2,
                                      H2C, cnt);

    proj2<<<32768, 256, 0, stream>>>(H2C, Pm, bP, out, 131071);
}

// Round 8
// 300.025 us; speedup vs baseline: 5.0873x; 5.0873x over previous
//
#include <hip/hip_runtime.h>
#include <cstdint>
#include <cstddef>

#define NCLS 5

typedef unsigned short ushort_t;
typedef __attribute__((ext_vector_type(8))) short short8v;   // 8 bf16 (4 VGPRs)
typedef __attribute__((ext_vector_type(4))) float f32x4;     // MFMA accumulator

__device__ __forceinline__ float sigf(float x) { return 1.0f / (1.0f + __expf(-x)); }

__device__ __forceinline__ unsigned short bf16_rne(float x) {
    unsigned u = __float_as_uint(x);
    u += 0x7FFFu + ((u >> 16) & 1u);
    return (unsigned short)(u >> 16);
}
__device__ __forceinline__ float bf16_f32(unsigned short h) {
    return __uint_as_float(((unsigned)h) << 16);
}

__device__ __forceinline__ void cvt_hilo(float4 f0, float4 f1, short8v& hi, short8v& lo) {
    float v[8] = { f0.x, f0.y, f0.z, f0.w, f1.x, f1.y, f1.z, f1.w };
#pragma unroll
    for (int e = 0; e < 8; ++e) {
        unsigned short h = bf16_rne(v[e]);
        unsigned short l = bf16_rne(v[e] - bf16_f32(h));
        hi[e] = (short)h; lo[e] = (short)l;
    }
}

// ---------------------------------------------------------------------------
// Weight prep (fragment-ordered, f1/f2 packed — verified in round 7).
// Level WtPL[cb 8][cc 16][slot 4][lane 64][e 8]:
//   band=cc>>3 (hi/lo), c8=cc&7, csel=c8>>2, kc=(c8&3)*32+kq, kq=(lane>>4)*8+e
//   slot 0..2 = Ui/Uo/Uu at K=csel*128+kc; slot 3 = csel? Uf2[kc] : Uf1[kc]
// Leaf WtPF[cb 8][cc 8][slot 3][lane][e]: band=cc>>2, kc=(cc&3)*32+kq
// ---------------------------------------------------------------------------
__global__ __launch_bounds__(256)
void prep_w(const float* __restrict__ Wi, const float* __restrict__ Wo,
            const float* __restrict__ Wu,
            const float* __restrict__ Ui, const float* __restrict__ Uo,
            const float* __restrict__ Uu, const float* __restrict__ Uf1,
            const float* __restrict__ Uf2,
            ushort_t* __restrict__ WtPL, ushort_t* __restrict__ WtPF)
{
    int b = blockIdx.x;
    if (b < 1024) {
        int idx = b * 256 + threadIdx.x;              // 262144
        int e = idx & 7, lane = (idx >> 3) & 63;
        int slot = (idx >> 9) & 3, cc = (idx >> 11) & 15, cb = idx >> 15;
        int j  = cb * 16 + (lane & 15);
        int kq = (lane >> 4) * 8 + e;
        int band = cc >> 3, c8 = cc & 7, csel = c8 >> 2;
        int kc = (c8 & 3) * 32 + kq;                  // [0,128)
        float x;
        if      (slot == 0) x = Ui[(csel * 128 + kc) * 128 + j];
        else if (slot == 1) x = Uo[(csel * 128 + kc) * 128 + j];
        else if (slot == 2) x = Uu[(csel * 128 + kc) * 128 + j];
        else                x = csel ? Uf2[kc * 128 + j] : Uf1[kc * 128 + j];
        unsigned short h = bf16_rne(x);
        if (band) h = bf16_rne(x - bf16_f32(h));
        WtPL[idx] = h;
    } else {
        int idx = (b - 1024) * 256 + threadIdx.x;     // 98304
        if (idx >= 98304) return;
        int e = idx & 7, lane = (idx >> 3) & 63;
        int rest = idx >> 9;
        int slot = rest % 3, cc = (rest / 3) & 7, cb = rest / 24;
        int j  = cb * 16 + (lane & 15);
        int kq = (lane >> 4) * 8 + e;
        int band = cc >> 2;
        int kc = (cc & 3) * 32 + kq;                  // [0,128)
        const float* W = (slot == 0) ? Wi : (slot == 1) ? Wo : Wu;
        float x = W[kc * 128 + j];
        unsigned short h = bf16_rne(x);
        if (band) h = bf16_rne(x - bf16_f32(h));
        WtPF[idx] = h;
    }
}

// ---------------------------------------------------------------------------
// Leaf: gather emb rows, hi/lo convert in-register, 3 gates, write H2/C2.
// 512 thr = 8 waves; wave wc owns 16-col j-block wc; BM=32 rows per block.
// H2/C2 node rows: 256 ushorts = [hi 128 | lo 128].
// ---------------------------------------------------------------------------
__global__ __launch_bounds__(512)
void leaf_stream(const int* __restrict__ words, const float* __restrict__ emb,
                 const ushort_t* __restrict__ WtPF,
                 const float* __restrict__ bi, const float* __restrict__ bo,
                 const float* __restrict__ bu,
                 ushort_t* __restrict__ H2out, ushort_t* __restrict__ C2out)
{
    const int tid = threadIdx.x, lane = tid & 63, wc = tid >> 6;
    const int l15 = lane & 15, l4 = lane >> 4;
    const int rb = blockIdx.x * 32;
    const ushort_t* slab = WtPF + (size_t)wc * 12288;

    const float* e0 = emb + (size_t)words[rb + l15] * 128;
    const float* e1 = emb + (size_t)words[rb + 16 + l15] * 128;

    f32x4 acc[2][3];
#pragma unroll
    for (int fr = 0; fr < 2; ++fr)
#pragma unroll
        for (int g = 0; g < 3; ++g) acc[fr][g] = (f32x4){0.f, 0.f, 0.f, 0.f};

#pragma unroll
    for (int cc = 0; cc < 4; ++cc) {
        const int k = cc * 32 + l4 * 8;
        short8v Ah0, Al0, Ah1, Al1;
        cvt_hilo(*(const float4*)(e0 + k), *(const float4*)(e0 + k + 4), Ah0, Al0);
        cvt_hilo(*(const float4*)(e1 + k), *(const float4*)(e1 + k + 4), Ah1, Al1);
#pragma unroll
        for (int s = 0; s < 3; ++s) {
            short8v Bh = *(const short8v*)(slab + (size_t)(cc * 3 + s) * 512 + lane * 8);
            short8v Bl = *(const short8v*)(slab + (size_t)((cc + 4) * 3 + s) * 512 + lane * 8);
            acc[0][s] = __builtin_amdgcn_mfma_f32_16x16x32_bf16(Ah0, Bh, acc[0][s], 0, 0, 0);
            acc[1][s] = __builtin_amdgcn_mfma_f32_16x16x32_bf16(Ah1, Bh, acc[1][s], 0, 0, 0);
            acc[0][s] = __builtin_amdgcn_mfma_f32_16x16x32_bf16(Al0, Bh, acc[0][s], 0, 0, 0);
            acc[1][s] = __builtin_amdgcn_mfma_f32_16x16x32_bf16(Al1, Bh, acc[1][s], 0, 0, 0);
            acc[0][s] = __builtin_amdgcn_mfma_f32_16x16x32_bf16(Ah0, Bl, acc[0][s], 0, 0, 0);
            acc[1][s] = __builtin_amdgcn_mfma_f32_16x16x32_bf16(Ah1, Bl, acc[1][s], 0, 0, 0);
        }
    }

    const int j = wc * 16 + l15;
    const float bi_ = bi[j], bo_ = bo[j], bu_ = bu[j];
#pragma unroll
    for (int fr = 0; fr < 2; ++fr)
#pragma unroll
        for (int v = 0; v < 4; ++v) {
            const int row = rb + fr * 16 + l4 * 4 + v;
            float iv = sigf(acc[fr][0][v] + bi_);
            float ov = sigf(acc[fr][1][v] + bo_);
            float uv = fmaxf(acc[fr][2][v] + bu_, 0.f);
            float c_ = iv * uv;
            float h_ = ov * fmaxf(c_, 0.f);
            unsigned short chi = bf16_rne(c_);
            unsigned short clo = bf16_rne(c_ - bf16_f32(chi));
            unsigned short hhi = bf16_rne(h_);
            unsigned short hlo = bf16_rne(h_ - bf16_f32(hhi));
            C2out[(size_t)row * 256 + j]       = chi;
            C2out[(size_t)row * 256 + 128 + j] = clo;
            H2out[(size_t)row * 256 + j]       = hhi;
            H2out[(size_t)row * 256 + 128 + j] = hlo;
        }
}

// ---------------------------------------------------------------------------
// Level stream kernel (m >= 4096). BM=32, 512 thr = 8 waves, grid m/32.
// H2in/C2in point at the child level's first node row.
// ---------------------------------------------------------------------------
__global__ __launch_bounds__(512)
void level_stream(const ushort_t* __restrict__ H2in, const ushort_t* __restrict__ C2in,
                  const ushort_t* __restrict__ WtPL,
                  const float* __restrict__ bUi, const float* __restrict__ bUo,
                  const float* __restrict__ bUu, const float* __restrict__ bf1,
                  const float* __restrict__ bf2,
                  ushort_t* __restrict__ H2out, ushort_t* __restrict__ C2out)
{
    const int tid = threadIdx.x, lane = tid & 63, wc = tid >> 6;
    const int l15 = lane & 15, l4 = lane >> 4;
    const int rb = blockIdx.x * 32;
    const ushort_t* slab = WtPL + (size_t)wc * 32768;

    const ushort_t* r0 = H2in + (size_t)(2 * (rb + l15)) * 256;
    const ushort_t* r1 = H2in + (size_t)(2 * (rb + 16 + l15)) * 256;

    f32x4 acc[2][5];
#pragma unroll
    for (int fr = 0; fr < 2; ++fr)
#pragma unroll
        for (int g = 0; g < 5; ++g) acc[fr][g] = (f32x4){0.f, 0.f, 0.f, 0.f};

#pragma unroll
    for (int cc = 0; cc < 8; ++cc) {
        const int csel = cc >> 2;
        const int aoff = csel * 256 + (cc & 3) * 32 + l4 * 8;
        short8v Ah0 = *(const short8v*)(r0 + aoff);
        short8v Ah1 = *(const short8v*)(r1 + aoff);
        short8v Al0 = *(const short8v*)(r0 + aoff + 128);
        short8v Al1 = *(const short8v*)(r1 + aoff + 128);
#pragma unroll
        for (int s = 0; s < 4; ++s) {
            const int col = (s < 3) ? s : 3 + csel;
            short8v Bh = *(const short8v*)(slab + (size_t)(cc * 4 + s) * 512 + lane * 8);
            short8v Bl = *(const short8v*)(slab + (size_t)((cc + 8) * 4 + s) * 512 + lane * 8);
            acc[0][col] = __builtin_amdgcn_mfma_f32_16x16x32_bf16(Ah0, Bh, acc[0][col], 0, 0, 0);
            acc[1][col] = __builtin_amdgcn_mfma_f32_16x16x32_bf16(Ah1, Bh, acc[1][col], 0, 0, 0);
            acc[0][col] = __builtin_amdgcn_mfma_f32_16x16x32_bf16(Al0, Bh, acc[0][col], 0, 0, 0);
            acc[1][col] = __builtin_amdgcn_mfma_f32_16x16x32_bf16(Al1, Bh, acc[1][col], 0, 0, 0);
            acc[0][col] = __builtin_amdgcn_mfma_f32_16x16x32_bf16(Ah0, Bl, acc[0][col], 0, 0, 0);
            acc[1][col] = __builtin_amdgcn_mfma_f32_16x16x32_bf16(Ah1, Bl, acc[1][col], 0, 0, 0);
        }
    }

    const int j = wc * 16 + l15;
    const float b0_ = bUi[j], b1_ = bUo[j], b2_ = bUu[j], b3_ = bf1[j], b4_ = bf2[j];
#pragma unroll
    for (int fr = 0; fr < 2; ++fr)
#pragma unroll
        for (int v = 0; v < 4; ++v) {
            const int row = rb + fr * 16 + l4 * 4 + v;
            float iv  = sigf(acc[fr][0][v] + b0_);
            float ov  = sigf(acc[fr][1][v] + b1_);
            float uv  = fmaxf(acc[fr][2][v] + b2_, 0.f);
            float f1v = sigf(acc[fr][3][v] + b3_);
            float f2v = sigf(acc[fr][4][v] + b4_);
            const ushort_t* cl = C2in + (size_t)(2 * row) * 256;
            float lC = bf16_f32(cl[j])       + bf16_f32(cl[128 + j]);
            float rC = bf16_f32(cl[256 + j]) + bf16_f32(cl[384 + j]);
            float c_ = fmaf(iv, uv, fmaf(f1v, lC, f2v * rC));
            float h_ = ov * fmaxf(c_, 0.f);
            unsigned short chi = bf16_rne(c_);
            unsigned short clo = bf16_rne(c_ - bf16_f32(chi));
            unsigned short hhi = bf16_rne(h_);
            unsigned short hlo = bf16_rne(h_ - bf16_f32(hhi));
            C2out[(size_t)row * 256 + j]       = chi;
            C2out[(size_t)row * 256 + 128 + j] = clo;
            H2out[(size_t)row * 256 + j]       = hhi;
            H2out[(size_t)row * 256 + 128 + j] = hlo;
        }
}

// ---------------------------------------------------------------------------
// Tiny level (m < 4096): 1 wave per block; grid (ceil(m/16), 8), cb=blockIdx.y.
// ---------------------------------------------------------------------------
__global__ __launch_bounds__(64)
void level_tiny(const ushort_t* __restrict__ H2in, const ushort_t* __restrict__ C2in,
                const ushort_t* __restrict__ WtPL,
                const float* __restrict__ bUi, const float* __restrict__ bUo,
                const float* __restrict__ bUu, const float* __restrict__ bf1,
                const float* __restrict__ bf2,
                ushort_t* __restrict__ H2out, ushort_t* __restrict__ C2out, int n)
{
    const int lane = threadIdx.x;
    const int l15 = lane & 15, l4 = lane >> 4;
    const int cb = blockIdx.y;
    const int rb = blockIdx.x * 16;
    const ushort_t* slab = WtPL + (size_t)cb * 32768;

    int prow = rb + l15; if (prow > n - 1) prow = n - 1;
    const ushort_t* r0 = H2in + (size_t)(2 * prow) * 256;

    f32x4 acc[5];
#pragma unroll
    for (int g = 0; g < 5; ++g) acc[g] = (f32x4){0.f, 0.f, 0.f, 0.f};

#pragma unroll
    for (int cc = 0; cc < 8; ++cc) {
        const int csel = cc >> 2;
        const int aoff = csel * 256 + (cc & 3) * 32 + l4 * 8;
        short8v Ah = *(const short8v*)(r0 + aoff);
        short8v Al = *(const short8v*)(r0 + aoff + 128);
#pragma unroll
        for (int s = 0; s < 4; ++s) {
            const int col = (s < 3) ? s : 3 + csel;
            short8v Bh = *(const short8v*)(slab + (size_t)(cc * 4 + s) * 512 + lane * 8);
            short8v Bl = *(const short8v*)(slab + (size_t)((cc + 8) * 4 + s) * 512 + lane * 8);
            acc[col] = __builtin_amdgcn_mfma_f32_16x16x32_bf16(Ah, Bh, acc[col], 0, 0, 0);
            acc[col] = __builtin_amdgcn_mfma_f32_16x16x32_bf16(Al, Bh, acc[col], 0, 0, 0);
            acc[col] = __builtin_amdgcn_mfma_f32_16x16x32_bf16(Ah, Bl, acc[col], 0, 0, 0);
        }
    }

    const int j = cb * 16 + l15;
    const float b0_ = bUi[j], b1_ = bUo[j], b2_ = bUu[j], b3_ = bf1[j], b4_ = bf2[j];
#pragma unroll
    for (int v = 0; v < 4; ++v) {
        const int row = rb + l4 * 4 + v;
        if (row < n) {
            float iv  = sigf(acc[0][v] + b0_);
            float ov  = sigf(acc[1][v] + b1_);
            float uv  = fmaxf(acc[2][v] + b2_, 0.f);
            float f1v = sigf(acc[3][v] + b3_);
            float f2v = sigf(acc[4][v] + b4_);
            const ushort_t* cl = C2in + (size_t)(2 * row) * 256;
            float lC = bf16_f32(cl[j])       + bf16_f32(cl[128 + j]);
            float rC = bf16_f32(cl[256 + j]) + bf16_f32(cl[384 + j]);
            float c_ = fmaf(iv, uv, fmaf(f1v, lC, f2v * rC));
            float h_ = ov * fmaxf(c_, 0.f);
            unsigned short chi = bf16_rne(c_);
            unsigned short clo = bf16_rne(c_ - bf16_f32(chi));
            unsigned short hhi = bf16_rne(h_);
            unsigned short hlo = bf16_rne(h_ - bf16_f32(hhi));
            C2out[(size_t)row * 256 + j]       = chi;
            C2out[(size_t)row * 256 + 128 + j] = clo;
            H2out[(size_t)row * 256 + j]       = hhi;
            H2out[(size_t)row * 256 + 128 + j] = hlo;
        }
    }
}

// ---------------------------------------------------------------------------
// Projection: out[r] = (hi+lo)[r] @ P + bP   (one wave per row)
// ---------------------------------------------------------------------------
__global__ __launch_bounds__(256)
void proj2(const ushort_t* __restrict__ H2, const float* __restrict__ P,
           const float* __restrict__ bP, float* __restrict__ out, int total)
{
    int wid  = blockIdx.x * 4 + (threadIdx.x >> 6);
    int lane = threadIdx.x & 63;
    if (wid >= total) return;
    const unsigned* hr = (const unsigned*)(H2 + (size_t)wid * 256);
    unsigned uh = hr[lane];
    unsigned ul = hr[64 + lane];
    float h0 = bf16_f32((unsigned short)(uh & 0xffffu)) + bf16_f32((unsigned short)(ul & 0xffffu));
    float h1 = bf16_f32((unsigned short)(uh >> 16)) + bf16_f32((unsigned short)(ul >> 16));
    const int k0 = 2 * lane, k1 = 2 * lane + 1;
    float a[NCLS];
#pragma unroll
    for (int c2 = 0; c2 < NCLS; ++c2)
        a[c2] = fmaf(h0, P[k0 * NCLS + c2], h1 * P[k1 * NCLS + c2]);
    for (int off = 32; off; off >>= 1)
#pragma unroll
        for (int c2 = 0; c2 < NCLS; ++c2) a[c2] += __shfl_down(a[c2], off, 64);
    if (lane == 0)
#pragma unroll
        for (int c2 = 0; c2 < NCLS; ++c2) out[(size_t)wid * NCLS + c2] = a[c2] + bP[c2];
}

// ---------------------------------------------------------------------------
// Host launcher.
// ws: WtPL@0 (512K) | WtPF@524288 (192K) | H2@1048576 (67.11M) | C2@68157440
// (67.11M) — ends 135.3 MB. Node rows write-once: leaf 0..65535, levels append.
// ---------------------------------------------------------------------------
extern "C" void kernel_launch(void* const* d_in, const int* in_sizes, int n_in,
                              void* d_out, int out_size, void* d_ws, size_t ws_size,
                              hipStream_t stream)
{
    const int*   words = (const int*)  d_in[0];
    const float* emb   = (const float*)d_in[1];
    const float* Wi  = (const float*)d_in[2];  const float* bi  = (const float*)d_in[3];
    const float* Wo  = (const float*)d_in[4];  const float* bo  = (const float*)d_in[5];
    const float* Wu  = (const float*)d_in[6];  const float* bu  = (const float*)d_in[7];
    const float* Ui  = (const float*)d_in[8];  const float* bUi = (const float*)d_in[9];
    const float* Uo  = (const float*)d_in[10]; const float* bUo = (const float*)d_in[11];
    const float* Uu  = (const float*)d_in[12]; const float* bUu = (const float*)d_in[13];
    const float* Uf1 = (const float*)d_in[14]; const float* bf1 = (const float*)d_in[15];
    const float* Uf2 = (const float*)d_in[16]; const float* bf2 = (const float*)d_in[17];
    const float* Pm  = (const float*)d_in[18]; const float* bP  = (const float*)d_in[19];
    float* out = (float*)d_out;

    ushort_t* WtPL = (ushort_t*)d_ws;
    ushort_t* WtPF = (ushort_t*)((char*)d_ws + 524288);
    ushort_t* H2   = (ushort_t*)((char*)d_ws + 1048576);
    ushort_t* C2   = (ushort_t*)((char*)d_ws + 68157440);

    prep_w<<<1408, 256, 0, stream>>>(Wi, Wo, Wu, Ui, Uo, Uu, Uf1, Uf2, WtPL, WtPF);

    leaf_stream<<<2048, 512, 0, stream>>>(words, emb, WtPF, bi, bo, bu, H2, C2);

    int off_prev = 0, off = 65536, m = 32768;
    while (m >= 1) {
        const ushort_t* h_in  = H2 + (size_t)off_prev * 256;
        const ushort_t* c_in  = C2 + (size_t)off_prev * 256;
        ushort_t* h_out = H2 + (size_t)off * 256;
        ushort_t* c_out = C2 + (size_t)off * 256;
        if (m >= 4096) {
            level_stream<<<m / 32, 512, 0, stream>>>(
                h_in, c_in, WtPL, bUi, bUo, bUu, bf1, bf2, h_out, c_out);
        } else {
            level_tiny<<<dim3((m + 15) / 16, 8), 64, 0, stream>>>(
                h_in, c_in, WtPL, bUi, bUo, bUu, bf1, bf2, h_out, c_out, m);
        }
        off_prev = off; off += m; m >>= 1;
    }

    proj2<<<32768, 256, 0, stream>>>(H2, Pm, bP, out, 131071);
}